// Round 8
// baseline (176.766 us; speedup 1.0000x reference)
//
#include <hip/hip_runtime.h>
#include <math.h>

#define NCAM 6
#define C_CH 64
#define HF   64
#define WF   176
#define GDIM 129
#define NY   4
#define NH   3
#define DD   128
#define WDIM 128
#define NP   (DD*WDIM)

#define PROWB (WF*C_CH*8)          // pbuf row stride, bytes (90112)
#define PCOLB (C_CH*8)             // pbuf col stride, bytes (512)
#define PIMGB ((size_t)HF*WF*C_CH*8)

// Packed box params, 32B = 8 dwords, laid out [nh][p][cam] (one voxel's 6 cams
// contiguous = 192B). dword0 = yT0|yB0<<8|xL0<<16|xR0<<24; 1..4 = wxL,wxR,wyT,wyB;
// 5 = area. Clamps baked into pbuf; boundary lerp weights are exactly 0 (pbuf padded).

__device__ __forceinline__ float bcf(int x) {
    return __builtin_bit_cast(float, x);
}

// ---------------- Kernel 1: row cumsum (axis=-1) -> channel-last rowsum ----------------
__global__ __launch_bounds__(256) void k_rowcum(const float* __restrict__ feat,
                                                float* __restrict__ rowsum)
{
    __shared__ float T[WF * 65];
    __shared__ float S[4][C_CH];
    __shared__ float OFF[4][C_CH];
    const int h   = blockIdx.x;
    const int n   = blockIdx.y;
    const int tid = threadIdx.x;

    for (int idx = tid; idx < C_CH * WF; idx += 256) {
        const int cc = idx / WF;
        const int w  = idx % WF;
        T[w*65 + cc] = feat[((size_t)(n*C_CH + cc)*HF + h)*WF + w];
    }
    __syncthreads();
    {
        const int cc = tid & 63, seg = tid >> 6;
        const int w0 = seg * 44;
        float run = 0.0f;
        #pragma unroll
        for (int i = 0; i < 44; ++i) {
            run += T[(w0 + i)*65 + cc];
            T[(w0 + i)*65 + cc] = run;
        }
        S[seg][cc] = run;
    }
    __syncthreads();
    {
        const int cc = tid & 63, seg = tid >> 6;
        float off = 0.0f;
        #pragma unroll
        for (int s = 0; s < 3; ++s)
            if (s < seg) off += S[s][cc];
        OFF[seg][cc] = off;
    }
    __syncthreads();
    float* outp = rowsum + (size_t)(n*HF + h) * (WF * C_CH);
    for (int idx = tid; idx < WF * C_CH; idx += 256) {
        const int w  = idx >> 6;
        const int cc = idx & 63;
        outp[idx] = T[w*65 + cc] + OFF[w/44][cc];
    }
}

// ---------------- Kernel 2: column cumsum -> x-pair integral buffer -------------------
// Block per (n,x). Register-scans columns x and min(x+1,WF-1) over h (4 segs of 16,
// LDS totals fix-up), emits pbuf[h][x][c] = float2(I[h][x][c], I[h][x+1][c]) with the
// x-clamp baked in. Fully coalesced 512B float2 stores.
__global__ __launch_bounds__(256) void k_paircol(const float* __restrict__ rowsum,
                                                 float2* __restrict__ pbuf)
{
    __shared__ float tA[4][C_CH], tB[4][C_CH];
    const int x  = blockIdx.x;
    const int n  = blockIdx.y;
    const int x1 = min(x + 1, WF - 1);
    const int c  = threadIdx.x & 63;
    const int hq = threadIdx.x >> 6;

    const float* base0 = rowsum + (size_t)n*HF*WF*C_CH + (size_t)x  * C_CH + c;
    const float* base1 = rowsum + (size_t)n*HF*WF*C_CH + (size_t)x1 * C_CH + c;
    float eA[16], eB[16];
    #pragma unroll
    for (int i = 0; i < 16; ++i) {
        const int h = hq*16 + i;
        eA[i] = base0[(size_t)h * (WF*C_CH)];
        eB[i] = base1[(size_t)h * (WF*C_CH)];
    }
    #pragma unroll
    for (int i = 1; i < 16; ++i) {
        eA[i] += eA[i-1];
        eB[i] += eB[i-1];
    }
    tA[hq][c] = eA[15];
    tB[hq][c] = eB[15];
    __syncthreads();
    float offA = 0.0f, offB = 0.0f;
    #pragma unroll
    for (int s = 0; s < 3; ++s)
        if (s < hq) { offA += tA[s][c]; offB += tB[s][c]; }
    float2* outp = pbuf + ((size_t)n*HF*WF + x) * C_CH + c;
    #pragma unroll
    for (int i = 0; i < 16; ++i) {
        const int h = hq*16 + i;
        outp[(size_t)h * (WF*C_CH)] = make_float2(eA[i] + offA, eB[i] + offB);
    }
}

// ---------------- Kernel 3: project 8 voxel corners + bbox -> packed params -----------
__global__ void k_boxproj(const float* __restrict__ ks,
                          const float* __restrict__ imu2cs,
                          const float* __restrict__ post_rots,
                          const float* __restrict__ post_trans,
                          const float* __restrict__ undists,
                          const float* __restrict__ grid,
                          int4* __restrict__ bp)
{
    const int idx = blockIdx.x * blockDim.x + threadIdx.x;
    if (idx >= NCAM * NH * NP) return;
    const int vox = idx / NCAM;
    const int n   = idx - vox * NCAM;
    const int nh  = vox / NP;
    const int p   = vox - nh * NP;
    const int d   = p / WDIM;
    const int wd  = p - d * WDIM;

    const float* k  = ks         + n * 9;
    const float* m  = imu2cs     + n * 12;
    const float* pr = post_rots  + n * 9;
    const float* pt = post_trans + n * 3;
    const float* D  = undists    + n * 7;

    float cal[12];
    #pragma unroll
    for (int i = 0; i < 3; ++i)
        #pragma unroll
        for (int j = 0; j < 4; ++j)
            cal[i*4+j] = k[i*3+0]*m[0*4+j] + k[i*3+1]*m[1*4+j] + k[i*3+2]*m[2*4+j];

    const float fx = k[0], fy = k[4], cx = k[2], cy = k[5];
    const float rfx = 1.0f / fx, rfy = 1.0f / fy;
    const bool fish = (D[6] == 1.0f);
    const float D0 = D[0], D1 = D[1], D2 = D[2], D3 = D[3], D4 = D[4], D5 = D[5];

    float left = 1e30f, right = -1e30f, top = 1e30f, bot = -1e30f;
    #pragma unroll
    for (int a = 0; a < 2; ++a) {
        const float vy = 2.0f - (float)(nh + a);   // ys = -arange(0,4)+2
        #pragma unroll
        for (int b = 0; b < 2; ++b) {
            #pragma unroll
            for (int cc = 0; cc < 2; ++cc) {
                const int gz = d + b, gx = wd + cc;
                const float vx = grid[(gz*GDIM + gx)*3 + 0];
                const float vz = grid[(gz*GDIM + gx)*3 + 2];

                const float hx = cal[0]*vx + cal[1]*vy + cal[2]*vz  + cal[3];
                const float hy = cal[4]*vx + cal[5]*vy + cal[6]*vz  + cal[7];
                const float hz = cal[8]*vx + cal[9]*vy + cal[10]*vz + cal[11];

                const float fl = (hz > 0.0f) ? 1.0f : 0.0f;
                const float rhz = __builtin_amdgcn_rcpf(hz);
                const float px = (hx * fl) * rhz;
                const float py = (hy * fl) * rhz;

                const float x = (px - cx) * rfx;
                const float y = (py - cy) * rfy;

                float xd, yd;
                if (fish) {
                    const float rr = sqrtf(x*x + y*y);
                    const float th = atanf(rr);
                    const float t2 = th * th;
                    const float t4 = t2 * t2;
                    const float rad = th * (1.0f + D0*t2 + D1*t4 + D2*(t2*t4) + D5*(t4*t4))
                                      * __builtin_amdgcn_rcpf(rr);
                    xd = x * rad * fx + cx;
                    yd = y * rad * fy + cy;
                } else {
                    const float r2 = x*x + y*y;
                    const float poly = 1.0f + D0*r2 + D1*r2*r2 + D2*r2*r2*r2;
                    const float xdd = x*poly + (2.0f*D3*x*y + D4*(r2 + 2.0f*x*x));
                    const float ydd = y*poly + (D3*(r2 + 2.0f*y*y) + 2.0f*D4*x*y);
                    xd = xdd * fx + cx;
                    yd = ydd * fy + cy;
                }
                xd *= fl; yd *= fl;

                const float qx = pr[0]*xd + pr[1]*yd + pt[0];
                const float qy = pr[3]*xd + pr[4]*yd + pt[1];
                const float ncx = fminf(fmaxf(2.0f*qx - 1.0f, -1.0f), 1.0f);
                const float ncy = fminf(fmaxf(2.0f*qy - 1.0f, -1.0f), 1.0f);

                left  = fminf(left,  ncx);  right = fmaxf(right, ncx);
                top   = fminf(top,   ncy);  bot   = fmaxf(bot,   ncy);
            }
        }
    }

    const float area = (right - left) * (bot - top) * (float)HF * (float)WF * 0.25f + 1e-6f;

    const float xLp = fminf(fmaxf((left  + 1.0f) * 0.5f * (float)(WF-1), 0.0f), (float)(WF-1));
    const float xRp = fminf(fmaxf((right + 1.0f) * 0.5f * (float)(WF-1), 0.0f), (float)(WF-1));
    const float yTp = fminf(fmaxf((top   + 1.0f) * 0.5f * (float)(HF-1), 0.0f), (float)(HF-1));
    const float yBp = fminf(fmaxf((bot   + 1.0f) * 0.5f * (float)(HF-1), 0.0f), (float)(HF-1));
    const float xL0 = floorf(xLp), xR0 = floorf(xRp), yT0 = floorf(yTp), yB0 = floorf(yBp);

    const int pyx = (int)yT0 | ((int)yB0 << 8) | ((int)xL0 << 16) | ((int)xR0 << 24);

    int4 o0, o1;
    o0.x = pyx;
    o0.y = __builtin_bit_cast(int, xLp - xL0);
    o0.z = __builtin_bit_cast(int, xRp - xR0);
    o0.w = __builtin_bit_cast(int, yTp - yT0);
    o1.x = __builtin_bit_cast(int, yBp - yB0);
    o1.y = __builtin_bit_cast(int, area);
    o1.z = 0; o1.w = 0;
    bp[(size_t)idx*2 + 0] = o0;
    bp[(size_t)idx*2 + 1] = o1;
}

// ---------------- Kernel 4: sample pair-integral, combine, max over cameras -----------
// 1536 blocks, XCD-swizzled contiguous bands. 4 waves/block, wave = 8 voxels,
// lane = channel. 8 dwordx2 loads/body (x-pair in-lane -> x-lerp without shuffles);
// camera-pair batching (16 float2 in flight); one-voxel-ahead param vector prefetch.
__global__ __launch_bounds__(256, 6) void k_sample(const float2* __restrict__ pbuf,
                                                   const int* __restrict__ bpi,
                                                   float* __restrict__ out)
{
    __shared__ float sm[32][65];
    const int bx   = blockIdx.x;
    const int xcd  = bx & 7;
    const int slot = bx >> 3;
    const int gt   = xcd * 192 + slot;          // contiguous tile band per XCD
    const int nh   = gt >> 9;
    const int p0   = (gt & 511) * 32;
    const int tid  = threadIdx.x;
    const int wave = __builtin_amdgcn_readfirstlane(tid >> 6);
    const int c    = tid & 63;
    const int pl   = (c < 48) ? c : (c - 48);    // dword index within 192B param block

    const int* bpw = bpi + (size_t)(nh*NP + p0 + wave*8) * 48;

    int vpc = bpw[pl];                            // params for j=0
    #pragma unroll 1
    for (int j = 0; j < 8; ++j) {
        int vpn = vpc;
        if (j < 7) vpn = bpw[(j + 1) * 48 + pl]; // prefetch next voxel's params

        float vmax = -3.402823466e38f;
        #pragma unroll
        for (int pr2 = 0; pr2 < 3; ++pr2) {
            const int camA = pr2*2, camB = pr2*2 + 1;
            const int fA = __builtin_amdgcn_readlane(vpc, camA*8 + 0);
            const float wxlA = bcf(__builtin_amdgcn_readlane(vpc, camA*8 + 1));
            const float wxrA = bcf(__builtin_amdgcn_readlane(vpc, camA*8 + 2));
            const float wytA = bcf(__builtin_amdgcn_readlane(vpc, camA*8 + 3));
            const float wybA = bcf(__builtin_amdgcn_readlane(vpc, camA*8 + 4));
            const float arA  = bcf(__builtin_amdgcn_readlane(vpc, camA*8 + 5));
            const int fB = __builtin_amdgcn_readlane(vpc, camB*8 + 0);
            const float wxlB = bcf(__builtin_amdgcn_readlane(vpc, camB*8 + 1));
            const float wxrB = bcf(__builtin_amdgcn_readlane(vpc, camB*8 + 2));
            const float wytB = bcf(__builtin_amdgcn_readlane(vpc, camB*8 + 3));
            const float wybB = bcf(__builtin_amdgcn_readlane(vpc, camB*8 + 4));
            const float arB  = bcf(__builtin_amdgcn_readlane(vpc, camB*8 + 5));

            float2 tA[8], tB[8];   // [row0..3][colL,colR]
            {
                const int yT = fA & 255, yB2 = (fA >> 8) & 255;
                const int xL = (fA >> 16) & 255, xR = (fA >> 24) & 255;
                const int r0 = yT * PROWB, r2 = yB2 * PROWB;
                const int cl = xL * PCOLB, cr = xR * PCOLB;
                const char* b = (const char*)pbuf + (size_t)camA * PIMGB + (size_t)c * 8;
                tA[0] = *(const float2*)(b + (size_t)(r0 + cl));
                tA[1] = *(const float2*)(b + (size_t)(r0 + cr));
                tA[2] = *(const float2*)(b + (size_t)(r0 + PROWB + cl));
                tA[3] = *(const float2*)(b + (size_t)(r0 + PROWB + cr));
                tA[4] = *(const float2*)(b + (size_t)(r2 + cl));
                tA[5] = *(const float2*)(b + (size_t)(r2 + cr));
                tA[6] = *(const float2*)(b + (size_t)(r2 + PROWB + cl));
                tA[7] = *(const float2*)(b + (size_t)(r2 + PROWB + cr));
            }
            {
                const int yT = fB & 255, yB2 = (fB >> 8) & 255;
                const int xL = (fB >> 16) & 255, xR = (fB >> 24) & 255;
                const int r0 = yT * PROWB, r2 = yB2 * PROWB;
                const int cl = xL * PCOLB, cr = xR * PCOLB;
                const char* b = (const char*)pbuf + (size_t)camB * PIMGB + (size_t)c * 8;
                tB[0] = *(const float2*)(b + (size_t)(r0 + cl));
                tB[1] = *(const float2*)(b + (size_t)(r0 + cr));
                tB[2] = *(const float2*)(b + (size_t)(r0 + PROWB + cl));
                tB[3] = *(const float2*)(b + (size_t)(r0 + PROWB + cr));
                tB[4] = *(const float2*)(b + (size_t)(r2 + cl));
                tB[5] = *(const float2*)(b + (size_t)(r2 + cr));
                tB[6] = *(const float2*)(b + (size_t)(r2 + PROWB + cl));
                tB[7] = *(const float2*)(b + (size_t)(r2 + PROWB + cr));
            }

            {
                const float A0 = fmaf(wxlA, tA[0].y - tA[0].x, tA[0].x);
                const float B0 = fmaf(wxrA, tA[1].y - tA[1].x, tA[1].x);
                const float A1 = fmaf(wxlA, tA[2].y - tA[2].x, tA[2].x);
                const float B1 = fmaf(wxrA, tA[3].y - tA[3].x, tA[3].x);
                const float A2 = fmaf(wxlA, tA[4].y - tA[4].x, tA[4].x);
                const float B2 = fmaf(wxrA, tA[5].y - tA[5].x, tA[5].x);
                const float A3 = fmaf(wxlA, tA[6].y - tA[6].x, tA[6].x);
                const float B3 = fmaf(wxrA, tA[7].y - tA[7].x, tA[7].x);
                const float d0 = A0 - B0, d1 = A1 - B1;
                const float e0 = B2 - A2, e1 = B3 - A3;
                const float s = fmaf(wytA, d1 - d0, d0) + fmaf(wybA, e1 - e0, e0);
                float v = s * __builtin_amdgcn_rcpf(arA);
                v = (arA > 1e-6f) ? v : 0.0f;    // reference: vox * (area > EPS)
                vmax = fmaxf(vmax, v);
            }
            {
                const float A0 = fmaf(wxlB, tB[0].y - tB[0].x, tB[0].x);
                const float B0 = fmaf(wxrB, tB[1].y - tB[1].x, tB[1].x);
                const float A1 = fmaf(wxlB, tB[2].y - tB[2].x, tB[2].x);
                const float B1 = fmaf(wxrB, tB[3].y - tB[3].x, tB[3].x);
                const float A2 = fmaf(wxlB, tB[4].y - tB[4].x, tB[4].x);
                const float B2 = fmaf(wxrB, tB[5].y - tB[5].x, tB[5].x);
                const float A3 = fmaf(wxlB, tB[6].y - tB[6].x, tB[6].x);
                const float B3 = fmaf(wxrB, tB[7].y - tB[7].x, tB[7].x);
                const float d0 = A0 - B0, d1 = A1 - B1;
                const float e0 = B2 - A2, e1 = B3 - A3;
                const float s = fmaf(wytB, d1 - d0, d0) + fmaf(wybB, e1 - e0, e0);
                float v = s * __builtin_amdgcn_rcpf(arB);
                v = (arB > 1e-6f) ? v : 0.0f;
                vmax = fmaxf(vmax, v);
            }
        }
        sm[wave*8 + j][c] = vmax;
        vpc = vpn;
    }
    __syncthreads();
    #pragma unroll
    for (int it = 0; it < 8; ++it) {
        const int idx = it*256 + tid;
        const int jj = idx & 31;
        const int cc = idx >> 5;
        out[(size_t)(cc*NH + nh)*NP + p0 + jj] = sm[jj][cc];
    }
}

extern "C" void kernel_launch(void* const* d_in, const int* in_sizes, int n_in,
                              void* d_out, int out_size, void* d_ws, size_t ws_size,
                              hipStream_t stream)
{
    const float* feats      = (const float*)d_in[0];  // [1,6,64,64,176]
    const float* ks         = (const float*)d_in[1];  // [1,6,3,3]
    const float* imu2cs     = (const float*)d_in[2];  // [1,6,3,4]
    const float* post_rots  = (const float*)d_in[3];  // [1,6,3,3]
    const float* post_trans = (const float*)d_in[4];  // [1,6,3]
    const float* undists    = (const float*)d_in[5];  // [1,6,7]
    const float* grid       = (const float*)d_in[6];  // [1,129,129,3]
    float* out = (float*)d_out;                       // [1,192,128,128]

    char* ws = (char*)d_ws;
    size_t off = 0;
    float* rowsum = (float*)(ws + off);
    off += (size_t)NCAM * HF * WF * C_CH * 4;
    off = (off + 255) & ~(size_t)255;
    float2* pbuf = (float2*)(ws + off);
    off += (size_t)NCAM * PIMGB + PROWB;              // +1 row pad: y-overreads (weight 0)
    off = (off + 255) & ~(size_t)255;
    int4* bp = (int4*)(ws + off);
    off += (size_t)NCAM * NH * NP * 32 + 256;
    (void)ws_size; (void)in_sizes; (void)n_in; (void)out_size;

    dim3 g1(HF, NCAM);
    k_rowcum<<<g1, 256, 0, stream>>>(feats, rowsum);

    dim3 g2(WF, NCAM);
    k_paircol<<<g2, 256, 0, stream>>>(rowsum, pbuf);

    dim3 g3((NCAM*NH*NP + 255)/256);
    k_boxproj<<<g3, 256, 0, stream>>>(ks, imu2cs, post_rots, post_trans, undists, grid, bp);

    dim3 g4(NP/32 * NH);   // 1536 blocks, 1D, XCD-swizzled inside
    k_sample<<<g4, 256, 0, stream>>>(pbuf, (const int*)bp, out);
}

// Round 9
// 172.007 us; speedup vs baseline: 1.0277x; 1.0277x over previous
//
#include <hip/hip_runtime.h>
#include <math.h>

#define NCAM 6
#define C_CH 64
#define HF   64
#define WF   176
#define GDIM 129
#define NY   4
#define NH   3
#define DD   128
#define WDIM 128
#define NP   (DD*WDIM)

#define ROWB (WF*C_CH*4)          // integral row stride, bytes (45056)
#define COLB (C_CH*4)             // integral col stride, bytes (256)
#define IMGB ((size_t)HF*WF*C_CH*4)

// Packed box params, 32B = 8 dwords, laid out [nh][p][cam] (one voxel's 6 cams
// contiguous = 192B). dword0 = yT0|yB0<<8|xL0<<16|xR0<<24; 1..4 = wxL,wxR,wyT,wyB;
// 5 = area. No clamps: boundary lerp weights are exactly 0 and integ is padded,
// so the (finite-garbage) overread rows/cols are multiplied by 0.

__device__ __forceinline__ float bcf(int x) {
    return __builtin_bit_cast(float, x);
}

// ---------------- Kernel 1: row cumsum (axis=-1) -> channel-last, into integ ----------
__global__ __launch_bounds__(256) void k_rowcum(const float* __restrict__ feat,
                                                float* __restrict__ integ)
{
    __shared__ float T[WF * 65];
    __shared__ float S[4][C_CH];
    __shared__ float OFF[4][C_CH];
    const int h   = blockIdx.x;
    const int n   = blockIdx.y;
    const int tid = threadIdx.x;

    for (int idx = tid; idx < C_CH * WF; idx += 256) {
        const int cc = idx / WF;
        const int w  = idx % WF;
        T[w*65 + cc] = feat[((size_t)(n*C_CH + cc)*HF + h)*WF + w];
    }
    __syncthreads();
    {
        const int cc = tid & 63, seg = tid >> 6;
        const int w0 = seg * 44;
        float run = 0.0f;
        #pragma unroll
        for (int i = 0; i < 44; ++i) {
            run += T[(w0 + i)*65 + cc];
            T[(w0 + i)*65 + cc] = run;
        }
        S[seg][cc] = run;
    }
    __syncthreads();
    {
        const int cc = tid & 63, seg = tid >> 6;
        float off = 0.0f;
        #pragma unroll
        for (int s = 0; s < 3; ++s)
            if (s < seg) off += S[s][cc];
        OFF[seg][cc] = off;
    }
    __syncthreads();
    float* outp = integ + (size_t)(n*HF + h) * (WF * C_CH);
    for (int idx = tid; idx < WF * C_CH; idx += 256) {
        const int w  = idx >> 6;
        const int cc = idx & 63;
        outp[idx] = T[w*65 + cc] + OFF[w/44][cc];
    }
}

// ---------------- Kernel 2: column cumsum IN PLACE -> integral [n][h][x][c] -----------
__global__ __launch_bounds__(256) void k_colcum(float* __restrict__ integ)
{
    __shared__ float tA[4][C_CH];
    const int x  = blockIdx.x;
    const int n  = blockIdx.y;
    const int c  = threadIdx.x & 63;
    const int hq = threadIdx.x >> 6;

    float* base = integ + (size_t)n*HF*WF*C_CH + (size_t)x * C_CH + c;
    float e[16];
    #pragma unroll
    for (int i = 0; i < 16; ++i)
        e[i] = base[(size_t)(hq*16 + i) * (WF*C_CH)];
    #pragma unroll
    for (int i = 1; i < 16; ++i)
        e[i] += e[i-1];
    tA[hq][c] = e[15];
    __syncthreads();
    float off = 0.0f;
    #pragma unroll
    for (int s = 0; s < 3; ++s)
        if (s < hq) off += tA[s][c];
    #pragma unroll
    for (int i = 0; i < 16; ++i)
        base[(size_t)(hq*16 + i) * (WF*C_CH)] = e[i] + off;
}

// ---------------- Kernel 3a: project UNIQUE grid corners (400K, not 14M) --------------
__global__ void k_project(const float* __restrict__ ks,
                          const float* __restrict__ imu2cs,
                          const float* __restrict__ post_rots,
                          const float* __restrict__ post_trans,
                          const float* __restrict__ undists,
                          const float* __restrict__ grid,
                          float2* __restrict__ ncbuf)
{
    const int n   = blockIdx.y;
    const int idx = blockIdx.x * blockDim.x + threadIdx.x;
    const int per = NY * GDIM * GDIM;
    if (idx >= per) return;
    const int ny  = idx / (GDIM * GDIM);
    const int rem = idx % (GDIM * GDIM);
    const int gz  = rem / GDIM;
    const int gx  = rem % GDIM;

    const float* k  = ks         + n * 9;
    const float* m  = imu2cs     + n * 12;
    const float* pr = post_rots  + n * 9;
    const float* pt = post_trans + n * 3;
    const float* D  = undists    + n * 7;

    float cal[12];
    #pragma unroll
    for (int i = 0; i < 3; ++i)
        #pragma unroll
        for (int j = 0; j < 4; ++j)
            cal[i*4+j] = k[i*3+0]*m[0*4+j] + k[i*3+1]*m[1*4+j] + k[i*3+2]*m[2*4+j];

    const float vx = grid[(gz*GDIM + gx)*3 + 0];
    const float vy = 2.0f - (float)ny;               // ys = -arange(0,4)+2
    const float vz = grid[(gz*GDIM + gx)*3 + 2];

    const float hx = cal[0]*vx + cal[1]*vy + cal[2]*vz  + cal[3];
    const float hy = cal[4]*vx + cal[5]*vy + cal[6]*vz  + cal[7];
    const float hz = cal[8]*vx + cal[9]*vy + cal[10]*vz + cal[11];

    const float fl = (hz > 0.0f) ? 1.0f : 0.0f;
    const float px = (hx * fl) / hz;
    const float py = (hy * fl) / hz;

    const float fx = k[0], fy = k[4], cx = k[2], cy = k[5];
    const float x = (px - cx) / fx;
    const float y = (py - cy) / fy;

    float xd, yd;
    if (D[6] == 1.0f) {
        const float r  = sqrtf(x*x + y*y);
        const float th = atanf(r);
        const float t2 = th * th;
        const float t4 = t2 * t2;
        const float rad = th * (1.0f + D[0]*t2 + D[1]*t4 + D[2]*(t2*t4) + D[5]*(t4*t4)) / r;
        xd = x * rad * fx + cx;
        yd = y * rad * fy + cy;
    } else {
        const float k1 = D[0], k2 = D[1], k3 = D[2], p1 = D[3], p2 = D[4];
        const float r2 = x*x + y*y;
        const float poly = 1.0f + k1*r2 + k2*r2*r2 + k3*r2*r2*r2;
        const float xdd = x*poly + (2.0f*p1*x*y + p2*(r2 + 2.0f*x*x));
        const float ydd = y*poly + (p1*(r2 + 2.0f*y*y) + 2.0f*p2*x*y);
        xd = xdd * fx + cx;
        yd = ydd * fy + cy;
    }
    xd *= fl; yd *= fl;

    const float qx = pr[0]*xd + pr[1]*yd + pt[0];
    const float qy = pr[3]*xd + pr[4]*yd + pt[1];
    const float ncx = fminf(fmaxf(2.0f*qx - 1.0f, -1.0f), 1.0f);
    const float ncy = fminf(fmaxf(2.0f*qy - 1.0f, -1.0f), 1.0f);
    ncbuf[((n*NY + ny)*GDIM + gz)*GDIM + gx] = make_float2(ncx, ncy);
}

// ---------------- Kernel 3b: bbox over 8 corners + pack params ------------------------
__global__ void k_boxparams(const float2* __restrict__ ncbuf, int4* __restrict__ bp)
{
    const int idx = blockIdx.x * blockDim.x + threadIdx.x;
    if (idx >= NCAM * NH * NP) return;
    const int vox = idx / NCAM;
    const int n   = idx - vox * NCAM;     // cam fastest -> coalesced 32B writes
    const int nh  = vox / NP;
    const int p   = vox - nh * NP;
    const int d   = p / WDIM;
    const int wd  = p - d * WDIM;

    float left = 1e30f, right = -1e30f, top = 1e30f, bot = -1e30f;
    #pragma unroll
    for (int a = 0; a < 2; ++a)
        #pragma unroll
        for (int b = 0; b < 2; ++b)
            #pragma unroll
            for (int cc = 0; cc < 2; ++cc) {
                const float2 v = ncbuf[((n*NY + nh + a)*GDIM + d + b)*GDIM + wd + cc];
                left  = fminf(left,  v.x);  right = fmaxf(right, v.x);
                top   = fminf(top,   v.y);  bot   = fmaxf(bot,   v.y);
            }

    const float area = (right - left) * (bot - top) * (float)HF * (float)WF * 0.25f + 1e-6f;

    const float xLp = fminf(fmaxf((left  + 1.0f) * 0.5f * (float)(WF-1), 0.0f), (float)(WF-1));
    const float xRp = fminf(fmaxf((right + 1.0f) * 0.5f * (float)(WF-1), 0.0f), (float)(WF-1));
    const float yTp = fminf(fmaxf((top   + 1.0f) * 0.5f * (float)(HF-1), 0.0f), (float)(HF-1));
    const float yBp = fminf(fmaxf((bot   + 1.0f) * 0.5f * (float)(HF-1), 0.0f), (float)(HF-1));
    const float xL0 = floorf(xLp), xR0 = floorf(xRp), yT0 = floorf(yTp), yB0 = floorf(yBp);

    const int pyx = (int)yT0 | ((int)yB0 << 8) | ((int)xL0 << 16) | ((int)xR0 << 24);

    int4 o0, o1;
    o0.x = pyx;
    o0.y = __builtin_bit_cast(int, xLp - xL0);
    o0.z = __builtin_bit_cast(int, xRp - xR0);
    o0.w = __builtin_bit_cast(int, yTp - yT0);
    o1.x = __builtin_bit_cast(int, yBp - yB0);
    o1.y = __builtin_bit_cast(int, area);
    o1.z = 0; o1.w = 0;
    bp[(size_t)idx*2 + 0] = o0;
    bp[(size_t)idx*2 + 1] = o1;
}

// ---------------- Kernel 4: half-wave voxel-paired sampling ---------------------------
// 1536 blocks, XCD-swizzled contiguous bands. Wave = 8 voxels done as 4 voxel-PAIRS:
// lanes 0-31 serve voxel A, lanes 32-63 voxel B; each lane loads float2 (2 channels).
// One dwordx2 instruction fetches one texel for BOTH voxels -> 48 vmem instrs/voxel
// (was 96) at identical 17MB footprint. Combine fully in-lane; per-half weight/offset
// selection via cndmask. One-pair-ahead param vector prefetch, readlane decode.
__global__ __launch_bounds__(256, 6) void k_sample(const float* __restrict__ integ,
                                                   const int* __restrict__ bpi,
                                                   float* __restrict__ out)
{
    __shared__ float sm[32][66];                 // 66: float2-aligned rows (264B)
    const int bx   = blockIdx.x;
    const int xcd  = bx & 7;
    const int slot = bx >> 3;
    const int gt   = xcd * 192 + slot;           // contiguous band per XCD
    const int nh   = gt >> 9;
    const int p0   = (gt & 511) * 32;
    const int tid  = threadIdx.x;
    const int wave = __builtin_amdgcn_readfirstlane(tid >> 6);
    const int c    = tid & 63;
    const bool hB  = (c >= 32);                  // half: voxel B
    const int lch  = c & 31;                     // channels 2*lch, 2*lch+1
    const int pl   = (c < 48) ? c : (c - 48);

    const int* bpw = bpi + (size_t)(nh*NP + p0 + wave*8) * 48;

    int vpA = bpw[pl];
    int vpB = bpw[48 + pl];
    #pragma unroll 1
    for (int i = 0; i < 4; ++i) {
        int vpA_n = vpA, vpB_n = vpB;
        if (i < 3) {
            vpA_n = bpw[(2*i + 2)*48 + pl];
            vpB_n = bpw[(2*i + 3)*48 + pl];
        }
        float vmx = -3.402823466e38f, vmy = -3.402823466e38f;
        #pragma unroll
        for (int cam = 0; cam < 6; ++cam) {
            const int   fA   = __builtin_amdgcn_readlane(vpA, cam*8 + 0);
            const float wxlA = bcf(__builtin_amdgcn_readlane(vpA, cam*8 + 1));
            const float wxrA = bcf(__builtin_amdgcn_readlane(vpA, cam*8 + 2));
            const float wytA = bcf(__builtin_amdgcn_readlane(vpA, cam*8 + 3));
            const float wybA = bcf(__builtin_amdgcn_readlane(vpA, cam*8 + 4));
            const float arA  = bcf(__builtin_amdgcn_readlane(vpA, cam*8 + 5));
            const int   fB   = __builtin_amdgcn_readlane(vpB, cam*8 + 0);
            const float wxlB = bcf(__builtin_amdgcn_readlane(vpB, cam*8 + 1));
            const float wxrB = bcf(__builtin_amdgcn_readlane(vpB, cam*8 + 2));
            const float wytB = bcf(__builtin_amdgcn_readlane(vpB, cam*8 + 3));
            const float wybB = bcf(__builtin_amdgcn_readlane(vpB, cam*8 + 4));
            const float arB  = bcf(__builtin_amdgcn_readlane(vpB, cam*8 + 5));

            const int rTA = (fA & 255) * ROWB,         rBA = ((fA >> 8) & 255) * ROWB;
            const int cLA = ((fA >> 16) & 255) * COLB, cRA = ((fA >> 24) & 255) * COLB;
            const int rTB = (fB & 255) * ROWB,         rBB = ((fB >> 8) & 255) * ROWB;
            const int cLB = ((fB >> 16) & 255) * COLB, cRB = ((fB >> 24) & 255) * COLB;

            const float wxl = hB ? wxlB : wxlA;
            const float wxr = hB ? wxrB : wxrA;
            const float wyt = hB ? wytB : wytA;
            const float wyb = hB ? wybB : wybA;
            const float ar  = hB ? arB  : arA;

            const char* base = (const char*)integ + (size_t)cam * IMGB + (size_t)(lch * 8);
            float2 t[16];
            #pragma unroll
            for (int r = 0; r < 4; ++r) {
                const int roA = ((r < 2) ? rTA : rBA) + ((r & 1) ? ROWB : 0);
                const int roB = ((r < 2) ? rTB : rBB) + ((r & 1) ? ROWB : 0);
                #pragma unroll
                for (int cc2 = 0; cc2 < 4; ++cc2) {
                    const int coA = ((cc2 < 2) ? cLA : cRA) + ((cc2 & 1) ? COLB : 0);
                    const int coB = ((cc2 < 2) ? cLB : cRB) + ((cc2 & 1) ? COLB : 0);
                    const int off = hB ? (roB + coB) : (roA + coA);
                    t[r*4 + cc2] = *(const float2*)(base + (size_t)off);
                }
            }

            // x-lerps (per lane, 2 channels)
            const float A0x = fmaf(wxl, t[1].x  - t[0].x,  t[0].x);
            const float A0y = fmaf(wxl, t[1].y  - t[0].y,  t[0].y);
            const float B0x = fmaf(wxr, t[3].x  - t[2].x,  t[2].x);
            const float B0y = fmaf(wxr, t[3].y  - t[2].y,  t[2].y);
            const float A1x = fmaf(wxl, t[5].x  - t[4].x,  t[4].x);
            const float A1y = fmaf(wxl, t[5].y  - t[4].y,  t[4].y);
            const float B1x = fmaf(wxr, t[7].x  - t[6].x,  t[6].x);
            const float B1y = fmaf(wxr, t[7].y  - t[6].y,  t[6].y);
            const float A2x = fmaf(wxl, t[9].x  - t[8].x,  t[8].x);
            const float A2y = fmaf(wxl, t[9].y  - t[8].y,  t[8].y);
            const float B2x = fmaf(wxr, t[11].x - t[10].x, t[10].x);
            const float B2y = fmaf(wxr, t[11].y - t[10].y, t[10].y);
            const float A3x = fmaf(wxl, t[13].x - t[12].x, t[12].x);
            const float A3y = fmaf(wxl, t[13].y - t[12].y, t[12].y);
            const float B3x = fmaf(wxr, t[15].x - t[14].x, t[14].x);
            const float B3y = fmaf(wxr, t[15].y - t[14].y, t[14].y);

            const float d0x = A0x - B0x, d1x = A1x - B1x;
            const float e0x = B2x - A2x, e1x = B3x - A3x;
            const float d0y = A0y - B0y, d1y = A1y - B1y;
            const float e0y = B2y - A2y, e1y = B3y - A3y;
            const float sx = fmaf(wyt, d1x - d0x, d0x) + fmaf(wyb, e1x - e0x, e0x);
            const float sy = fmaf(wyt, d1y - d0y, d0y) + fmaf(wyb, e1y - e0y, e0y);
            const float ia = __builtin_amdgcn_rcpf(ar);
            const bool ok = (ar > 1e-6f);
            vmx = fmaxf(vmx, ok ? sx * ia : 0.0f);
            vmy = fmaxf(vmy, ok ? sy * ia : 0.0f);
        }
        const int vox = wave*8 + 2*i + (hB ? 1 : 0);
        *(float2*)&sm[vox][2*lch] = make_float2(vmx, vmy);
        vpA = vpA_n; vpB = vpB_n;
    }
    __syncthreads();
    #pragma unroll
    for (int it = 0; it < 8; ++it) {
        const int idx = it*256 + tid;
        const int jj = idx & 31;
        const int cc = idx >> 5;
        out[(size_t)(cc*NH + nh)*NP + p0 + jj] = sm[jj][cc];
    }
}

extern "C" void kernel_launch(void* const* d_in, const int* in_sizes, int n_in,
                              void* d_out, int out_size, void* d_ws, size_t ws_size,
                              hipStream_t stream)
{
    const float* feats      = (const float*)d_in[0];  // [1,6,64,64,176]
    const float* ks         = (const float*)d_in[1];  // [1,6,3,3]
    const float* imu2cs     = (const float*)d_in[2];  // [1,6,3,4]
    const float* post_rots  = (const float*)d_in[3];  // [1,6,3,3]
    const float* post_trans = (const float*)d_in[4];  // [1,6,3]
    const float* undists    = (const float*)d_in[5];  // [1,6,7]
    const float* grid       = (const float*)d_in[6];  // [1,129,129,3]
    float* out = (float*)d_out;                       // [1,192,128,128]

    char* ws = (char*)d_ws;
    size_t off = 0;
    float* integ = (float*)(ws + off);                // rowsum then integral (in place)
    off += (size_t)NCAM * IMGB + ROWB + 65536;        // pad: clamp-free overreads (x0 wt)
    off = (off + 255) & ~(size_t)255;
    float2* ncbuf = (float2*)(ws + off);
    off += sizeof(float2) * (size_t)NCAM * NY * GDIM * GDIM;
    off = (off + 255) & ~(size_t)255;
    int4* bp = (int4*)(ws + off);
    off += (size_t)NCAM * NH * NP * 32 + 256;
    (void)ws_size; (void)in_sizes; (void)n_in; (void)out_size;

    dim3 g1(HF, NCAM);
    k_rowcum<<<g1, 256, 0, stream>>>(feats, integ);

    dim3 g2(WF, NCAM);
    k_colcum<<<g2, 256, 0, stream>>>(integ);

    dim3 g3((NY*GDIM*GDIM + 255)/256, NCAM);
    k_project<<<g3, 256, 0, stream>>>(ks, imu2cs, post_rots, post_trans, undists, grid, ncbuf);

    dim3 g4((NCAM*NH*NP + 255)/256);
    k_boxparams<<<g4, 256, 0, stream>>>(ncbuf, bp);

    dim3 g5(NP/32 * NH);   // 1536 blocks, XCD-swizzled inside
    k_sample<<<g5, 256, 0, stream>>>(integ, (const int*)bp, out);
}

// Round 10
// 143.257 us; speedup vs baseline: 1.2339x; 1.2007x over previous
//
#include <hip/hip_runtime.h>
#include <math.h>

#define NCAM 6
#define C_CH 64
#define HF   64
#define WF   176
#define GDIM 129
#define NY   4
#define NH   3
#define DD   128
#define WDIM 128
#define NP   (DD*WDIM)

#define ROWB (WF*C_CH*4)          // integral row stride, bytes (45056)
#define COLB (C_CH*4)             // integral col stride, bytes (256)
#define IMGB ((size_t)HF*WF*C_CH*4)

// Packed box params, 32B = 8 dwords, laid out [vox][cam] (one voxel's 6 cams
// contiguous = 192B). dword0 = yT0|yB0<<8|xL0<<16|xR0<<24; 1..4 = wxL,wxR,wyT,wyB;
// 5 = area. No clamps on +1 offsets: boundary lerp weights are exactly 0 and integ
// is padded, so overread rows/cols are finite-garbage × 0.

__device__ __forceinline__ float bcf(int x) {
    return __builtin_bit_cast(float, x);
}

// ---------------- Kernel 1: FUSED row-cumsum (384 blocks) || boxproj (1152 blocks) ----
// The two jobs are independent (rowcum: feat->integ; boxproj: calib->bp); fusing them
// into one launch removes one ~10us graph-node overhead.
__global__ __launch_bounds__(256) void k_prep(const float* __restrict__ feat,
                                              float* __restrict__ integ,
                                              const float* __restrict__ ks,
                                              const float* __restrict__ imu2cs,
                                              const float* __restrict__ post_rots,
                                              const float* __restrict__ post_trans,
                                              const float* __restrict__ undists,
                                              const float* __restrict__ grid,
                                              int4* __restrict__ bp)
{
    __shared__ float T[WF * 65];
    __shared__ float S[4][C_CH];
    __shared__ float OFF[4][C_CH];
    const int bx  = blockIdx.x;
    const int tid = threadIdx.x;

    if (bx < HF * NCAM) {
        // ---- row cumsum (axis=-1) -> channel-last, into integ ----
        const int n = bx / HF;
        const int h = bx % HF;

        for (int idx = tid; idx < C_CH * WF; idx += 256) {
            const int cc = idx / WF;
            const int w  = idx % WF;
            T[w*65 + cc] = feat[((size_t)(n*C_CH + cc)*HF + h)*WF + w];
        }
        __syncthreads();
        {
            const int cc = tid & 63, seg = tid >> 6;
            const int w0 = seg * 44;
            float run = 0.0f;
            #pragma unroll
            for (int i = 0; i < 44; ++i) {
                run += T[(w0 + i)*65 + cc];
                T[(w0 + i)*65 + cc] = run;
            }
            S[seg][cc] = run;
        }
        __syncthreads();
        {
            const int cc = tid & 63, seg = tid >> 6;
            float off = 0.0f;
            #pragma unroll
            for (int s = 0; s < 3; ++s)
                if (s < seg) off += S[s][cc];
            OFF[seg][cc] = off;
        }
        __syncthreads();
        float* outp = integ + (size_t)(n*HF + h) * (WF * C_CH);
        for (int idx = tid; idx < WF * C_CH; idx += 256) {
            const int w  = idx >> 6;
            const int cc = idx & 63;
            outp[idx] = T[w*65 + cc] + OFF[w/44][cc];
        }
        return;
    }

    // ---- boxproj: project 8 voxel corners + bbox -> packed params ----
    const int idx = (bx - HF*NCAM) * 256 + tid;
    if (idx >= NCAM * NH * NP) return;
    const int vox = idx / NCAM;
    const int n   = idx - vox * NCAM;     // cam fastest -> coalesced 32B writes
    const int nh  = vox / NP;
    const int p   = vox - nh * NP;
    const int d   = p / WDIM;
    const int wd  = p - d * WDIM;

    const float* k  = ks         + n * 9;
    const float* m  = imu2cs     + n * 12;
    const float* pr = post_rots  + n * 9;
    const float* pt = post_trans + n * 3;
    const float* D  = undists    + n * 7;

    float cal[12];
    #pragma unroll
    for (int i = 0; i < 3; ++i)
        #pragma unroll
        for (int j = 0; j < 4; ++j)
            cal[i*4+j] = k[i*3+0]*m[0*4+j] + k[i*3+1]*m[1*4+j] + k[i*3+2]*m[2*4+j];

    const float fx = k[0], fy = k[4], cx = k[2], cy = k[5];
    const float rfx = 1.0f / fx, rfy = 1.0f / fy;
    const bool fish = (D[6] == 1.0f);
    const float D0 = D[0], D1 = D[1], D2 = D[2], D3 = D[3], D4 = D[4], D5 = D[5];

    float left = 1e30f, right = -1e30f, top = 1e30f, bot = -1e30f;
    #pragma unroll
    for (int a = 0; a < 2; ++a) {
        const float vy = 2.0f - (float)(nh + a);   // ys = -arange(0,4)+2
        #pragma unroll
        for (int b = 0; b < 2; ++b) {
            #pragma unroll
            for (int cc = 0; cc < 2; ++cc) {
                const int gz = d + b, gx = wd + cc;
                const float vx = grid[(gz*GDIM + gx)*3 + 0];
                const float vz = grid[(gz*GDIM + gx)*3 + 2];

                const float hx = cal[0]*vx + cal[1]*vy + cal[2]*vz  + cal[3];
                const float hy = cal[4]*vx + cal[5]*vy + cal[6]*vz  + cal[7];
                const float hz = cal[8]*vx + cal[9]*vy + cal[10]*vz + cal[11];

                const float fl = (hz > 0.0f) ? 1.0f : 0.0f;
                const float px = (hx * fl) / hz;
                const float py = (hy * fl) / hz;

                const float x = (px - cx) * rfx;
                const float y = (py - cy) * rfy;

                float xd, yd;
                if (fish) {
                    const float rr = sqrtf(x*x + y*y);
                    const float th = atanf(rr);
                    const float t2 = th * th;
                    const float t4 = t2 * t2;
                    const float rad = th * (1.0f + D0*t2 + D1*t4 + D2*(t2*t4) + D5*(t4*t4)) / rr;
                    xd = x * rad * fx + cx;
                    yd = y * rad * fy + cy;
                } else {
                    const float r2 = x*x + y*y;
                    const float poly = 1.0f + D0*r2 + D1*r2*r2 + D2*r2*r2*r2;
                    const float xdd = x*poly + (2.0f*D3*x*y + D4*(r2 + 2.0f*x*x));
                    const float ydd = y*poly + (D3*(r2 + 2.0f*y*y) + 2.0f*D4*x*y);
                    xd = xdd * fx + cx;
                    yd = ydd * fy + cy;
                }
                xd *= fl; yd *= fl;

                const float qx = pr[0]*xd + pr[1]*yd + pt[0];
                const float qy = pr[3]*xd + pr[4]*yd + pt[1];
                const float ncx = fminf(fmaxf(2.0f*qx - 1.0f, -1.0f), 1.0f);
                const float ncy = fminf(fmaxf(2.0f*qy - 1.0f, -1.0f), 1.0f);

                left  = fminf(left,  ncx);  right = fmaxf(right, ncx);
                top   = fminf(top,   ncy);  bot   = fmaxf(bot,   ncy);
            }
        }
    }

    const float area = (right - left) * (bot - top) * (float)HF * (float)WF * 0.25f + 1e-6f;

    const float xLp = fminf(fmaxf((left  + 1.0f) * 0.5f * (float)(WF-1), 0.0f), (float)(WF-1));
    const float xRp = fminf(fmaxf((right + 1.0f) * 0.5f * (float)(WF-1), 0.0f), (float)(WF-1));
    const float yTp = fminf(fmaxf((top   + 1.0f) * 0.5f * (float)(HF-1), 0.0f), (float)(HF-1));
    const float yBp = fminf(fmaxf((bot   + 1.0f) * 0.5f * (float)(HF-1), 0.0f), (float)(HF-1));
    const float xL0 = floorf(xLp), xR0 = floorf(xRp), yT0 = floorf(yTp), yB0 = floorf(yBp);

    const int pyx = (int)yT0 | ((int)yB0 << 8) | ((int)xL0 << 16) | ((int)xR0 << 24);

    int4 o0, o1;
    o0.x = pyx;
    o0.y = __builtin_bit_cast(int, xLp - xL0);
    o0.z = __builtin_bit_cast(int, xRp - xR0);
    o0.w = __builtin_bit_cast(int, yTp - yT0);
    o1.x = __builtin_bit_cast(int, yBp - yB0);
    o1.y = __builtin_bit_cast(int, area);
    o1.z = 0; o1.w = 0;
    bp[(size_t)idx*2 + 0] = o0;
    bp[(size_t)idx*2 + 1] = o1;
}

// ---------------- Kernel 2: column cumsum IN PLACE -> integral [n][h][x][c] -----------
__global__ __launch_bounds__(256) void k_colcum(float* __restrict__ integ)
{
    __shared__ float tA[4][C_CH];
    const int x  = blockIdx.x;
    const int n  = blockIdx.y;
    const int c  = threadIdx.x & 63;
    const int hq = threadIdx.x >> 6;

    float* base = integ + (size_t)n*HF*WF*C_CH + (size_t)x * C_CH + c;
    float e[16];
    #pragma unroll
    for (int i = 0; i < 16; ++i)
        e[i] = base[(size_t)(hq*16 + i) * (WF*C_CH)];
    #pragma unroll
    for (int i = 1; i < 16; ++i)
        e[i] += e[i-1];
    tA[hq][c] = e[15];
    __syncthreads();
    float off = 0.0f;
    #pragma unroll
    for (int s = 0; s < 3; ++s)
        if (s < hq) off += tA[s][c];
    #pragma unroll
    for (int i = 0; i < 16; ++i)
        base[(size_t)(hq*16 + i) * (WF*C_CH)] = e[i] + off;
}

// ---------------- Kernel 3: sample integral image, combine, max over cameras ----------
// EXACT R7 structure (measured 48.1us): 1536 blocks XCD-swizzled into contiguous
// per-XCD voxel bands; 4 waves/block, wave = 8 voxels, lane = channel; camera-PAIR
// batching (32 dword texel loads in flight); one-voxel-ahead vector prefetch of the
// packed params, decoded to the scalar pipe via readlane. No cross-lane data ops.
__global__ __launch_bounds__(256, 6) void k_sample(const float* __restrict__ integ,
                                                   const int* __restrict__ bpi,
                                                   float* __restrict__ out)
{
    __shared__ float sm[32][65];
    const int bx   = blockIdx.x;
    const int xcd  = bx & 7;
    const int slot = bx >> 3;
    const int gt   = xcd * 192 + slot;          // contiguous tile band per XCD
    const int nh   = gt >> 9;
    const int p0   = (gt & 511) * 32;
    const int tid  = threadIdx.x;
    const int wave = __builtin_amdgcn_readfirstlane(tid >> 6);
    const int c    = tid & 63;
    const int pl   = (c < 48) ? c : (c - 48);    // dword index within 192B param block

    const int* bpw = bpi + (size_t)(nh*NP + p0 + wave*8) * 48;

    int vpc = bpw[pl];                            // params for j=0
    #pragma unroll 1
    for (int j = 0; j < 8; ++j) {
        int vpn = vpc;
        if (j < 7) vpn = bpw[(j + 1) * 48 + pl]; // prefetch next voxel's params

        float vmax = -3.402823466e38f;
        #pragma unroll
        for (int pr2 = 0; pr2 < 3; ++pr2) {
            const int camA = pr2*2, camB = pr2*2 + 1;
            const int fA = __builtin_amdgcn_readlane(vpc, camA*8 + 0);
            const float wxlA = bcf(__builtin_amdgcn_readlane(vpc, camA*8 + 1));
            const float wxrA = bcf(__builtin_amdgcn_readlane(vpc, camA*8 + 2));
            const float wytA = bcf(__builtin_amdgcn_readlane(vpc, camA*8 + 3));
            const float wybA = bcf(__builtin_amdgcn_readlane(vpc, camA*8 + 4));
            const float arA  = bcf(__builtin_amdgcn_readlane(vpc, camA*8 + 5));
            const int fB = __builtin_amdgcn_readlane(vpc, camB*8 + 0);
            const float wxlB = bcf(__builtin_amdgcn_readlane(vpc, camB*8 + 1));
            const float wxrB = bcf(__builtin_amdgcn_readlane(vpc, camB*8 + 2));
            const float wytB = bcf(__builtin_amdgcn_readlane(vpc, camB*8 + 3));
            const float wybB = bcf(__builtin_amdgcn_readlane(vpc, camB*8 + 4));
            const float arB  = bcf(__builtin_amdgcn_readlane(vpc, camB*8 + 5));

            float tA[16], tB[16];
            {
                const int yT = fA & 255, yB2 = (fA >> 8) & 255;
                const int xL = (fA >> 16) & 255, xR = (fA >> 24) & 255;
                const int r0 = yT * ROWB, r2 = yB2 * ROWB;
                const int c0 = xL * COLB, c2 = xR * COLB;
                const char* b = (const char*)integ + (size_t)camA * IMGB;
                #pragma unroll
                for (int rr = 0; rr < 4; ++rr) {
                    const int ro = ((rr < 2) ? r0 : r2) + ((rr & 1) ? ROWB : 0);
                    #pragma unroll
                    for (int cc2 = 0; cc2 < 4; ++cc2) {
                        const int co = ((cc2 < 2) ? c0 : c2) + ((cc2 & 1) ? COLB : 0);
                        tA[rr*4 + cc2] = ((const float*)(b + (size_t)(ro + co)))[c];
                    }
                }
            }
            {
                const int yT = fB & 255, yB2 = (fB >> 8) & 255;
                const int xL = (fB >> 16) & 255, xR = (fB >> 24) & 255;
                const int r0 = yT * ROWB, r2 = yB2 * ROWB;
                const int c0 = xL * COLB, c2 = xR * COLB;
                const char* b = (const char*)integ + (size_t)camB * IMGB;
                #pragma unroll
                for (int rr = 0; rr < 4; ++rr) {
                    const int ro = ((rr < 2) ? r0 : r2) + ((rr & 1) ? ROWB : 0);
                    #pragma unroll
                    for (int cc2 = 0; cc2 < 4; ++cc2) {
                        const int co = ((cc2 < 2) ? c0 : c2) + ((cc2 & 1) ? COLB : 0);
                        tB[rr*4 + cc2] = ((const float*)(b + (size_t)(ro + co)))[c];
                    }
                }
            }

            {
                const float A0 = fmaf(wxlA, tA[1]  - tA[0],  tA[0]);
                const float B0 = fmaf(wxrA, tA[3]  - tA[2],  tA[2]);
                const float A1 = fmaf(wxlA, tA[5]  - tA[4],  tA[4]);
                const float B1 = fmaf(wxrA, tA[7]  - tA[6],  tA[6]);
                const float A2 = fmaf(wxlA, tA[9]  - tA[8],  tA[8]);
                const float B2 = fmaf(wxrA, tA[11] - tA[10], tA[10]);
                const float A3 = fmaf(wxlA, tA[13] - tA[12], tA[12]);
                const float B3 = fmaf(wxrA, tA[15] - tA[14], tA[14]);
                const float d0 = A0 - B0, d1 = A1 - B1;
                const float e0 = B2 - A2, e1 = B3 - A3;
                const float s = fmaf(wytA, d1 - d0, d0) + fmaf(wybA, e1 - e0, e0);
                float v = s * __builtin_amdgcn_rcpf(arA);
                v = (arA > 1e-6f) ? v : 0.0f;    // reference: vox * (area > EPS)
                vmax = fmaxf(vmax, v);
            }
            {
                const float A0 = fmaf(wxlB, tB[1]  - tB[0],  tB[0]);
                const float B0 = fmaf(wxrB, tB[3]  - tB[2],  tB[2]);
                const float A1 = fmaf(wxlB, tB[5]  - tB[4],  tB[4]);
                const float B1 = fmaf(wxrB, tB[7]  - tB[6],  tB[6]);
                const float A2 = fmaf(wxlB, tB[9]  - tB[8],  tB[8]);
                const float B2 = fmaf(wxrB, tB[11] - tB[10], tB[10]);
                const float A3 = fmaf(wxlB, tB[13] - tB[12], tB[12]);
                const float B3 = fmaf(wxrB, tB[15] - tB[14], tB[14]);
                const float d0 = A0 - B0, d1 = A1 - B1;
                const float e0 = B2 - A2, e1 = B3 - A3;
                const float s = fmaf(wytB, d1 - d0, d0) + fmaf(wybB, e1 - e0, e0);
                float v = s * __builtin_amdgcn_rcpf(arB);
                v = (arB > 1e-6f) ? v : 0.0f;
                vmax = fmaxf(vmax, v);
            }
        }
        sm[wave*8 + j][c] = vmax;
        vpc = vpn;
    }
    __syncthreads();
    #pragma unroll
    for (int it = 0; it < 8; ++it) {
        const int idx = it*256 + tid;
        const int jj = idx & 31;
        const int cc = idx >> 5;
        out[(size_t)(cc*NH + nh)*NP + p0 + jj] = sm[jj][cc];
    }
}

extern "C" void kernel_launch(void* const* d_in, const int* in_sizes, int n_in,
                              void* d_out, int out_size, void* d_ws, size_t ws_size,
                              hipStream_t stream)
{
    const float* feats      = (const float*)d_in[0];  // [1,6,64,64,176]
    const float* ks         = (const float*)d_in[1];  // [1,6,3,3]
    const float* imu2cs     = (const float*)d_in[2];  // [1,6,3,4]
    const float* post_rots  = (const float*)d_in[3];  // [1,6,3,3]
    const float* post_trans = (const float*)d_in[4];  // [1,6,3]
    const float* undists    = (const float*)d_in[5];  // [1,6,7]
    const float* grid       = (const float*)d_in[6];  // [1,129,129,3]
    float* out = (float*)d_out;                       // [1,192,128,128]

    char* ws = (char*)d_ws;
    size_t off = 0;
    float* integ = (float*)(ws + off);                // rowsum then integral (in place)
    off += (size_t)NCAM * IMGB + ROWB + 65536;        // pad: clamp-free overreads (x0 wt)
    off = (off + 255) & ~(size_t)255;
    int4* bp = (int4*)(ws + off);
    off += (size_t)NCAM * NH * NP * 32 + 256;
    (void)ws_size; (void)in_sizes; (void)n_in; (void)out_size;

    // K1: fused row-cumsum (384 blocks) || boxproj (1152 blocks)
    dim3 g1(HF*NCAM + (NCAM*NH*NP + 255)/256);
    k_prep<<<g1, 256, 0, stream>>>(feats, integ, ks, imu2cs, post_rots, post_trans,
                                   undists, grid, bp);

    // K2: column cumsum in place
    dim3 g2(WF, NCAM);
    k_colcum<<<g2, 256, 0, stream>>>(integ);

    // K3: sampling (R7-exact)
    dim3 g3(NP/32 * NH);   // 1536 blocks, XCD-swizzled inside
    k_sample<<<g3, 256, 0, stream>>>(integ, (const int*)bp, out);
}